// Round 1
// baseline (198.488 us; speedup 1.0000x reference)
//
#include <hip/hip_runtime.h>
#include <math.h>

#define NTHREADS 256

// jax.nn.softplus(x) = max(x,0) + log1p(exp(-|x|))
__device__ __forceinline__ float softplus_f(float v) {
    return fmaxf(v, 0.0f) + log1pf(expf(-fabsf(v)));
}

// LDS layout (float indices)
#define L_W    0      // [64][64]  W[k*64+j] = sp(EX[k][j]) - sp(IN[k][j])
#define L_H    4096   // [64][8]   sp(w_hid2out)
#define L_C    4608   // [4][64]   M - sp(w_in2hid)
#define L_P4   4864   // [64]      a^4
#define L_Q    4928   // [64]      1+a+a^2+a^3
#define L_TH   4992   // [64]      th_hid
#define L_SM   5056   // dec_in[4] th_in[4] dec_out[8] th_out[8]
#define L_SW   5080   // [128]     sp(gj_w)
#define L_TOT  5208

__global__ __launch_bounds__(NTHREADS) void twc_fused(
    const float* __restrict__ x,
    const float* __restrict__ hidE0,
    const float* __restrict__ hidO0,
    const float* __restrict__ outE0,
    const float* __restrict__ w_in2hid,
    const float* __restrict__ w_hid_IN,
    const float* __restrict__ w_hid_EX,
    const float* __restrict__ w_hid2out,
    const float* __restrict__ gj_w,
    const float* __restrict__ th_in,
    const float* __restrict__ dec_in,
    const float* __restrict__ th_hid,
    const float* __restrict__ dec_hid,
    const float* __restrict__ th_out,
    const float* __restrict__ dec_out,
    const int* __restrict__ gj_src,
    const int* __restrict__ gj_dst,
    float* __restrict__ out, int B)
{
    __shared__ __align__(16) float s[L_TOT];
    __shared__ int ssrc[128], sdst[128];
    const int t = threadIdx.x;

    // ---- phase A: per-block weight transform into LDS ----
    for (int i = t; i < 4096; i += NTHREADS)
        s[L_W + i] = softplus_f(w_hid_EX[i]) - softplus_f(w_hid_IN[i]);
    for (int i = t; i < 512; i += NTHREADS)
        s[L_H + i] = softplus_f(w_hid2out[i]);
    if (t < 128) { s[L_SW + t] = softplus_f(gj_w[t]); ssrc[t] = gj_src[t]; sdst[t] = gj_dst[t]; }
    if (t < 64)  { s[L_TH + t] = th_hid[t]; }
    if (t < 4)   { s[L_SM + t] = dec_in[t]; s[L_SM + 4 + t] = th_in[t]; }
    if (t < 8)   { s[L_SM + 8 + t] = dec_out[t]; s[L_SM + 16 + t] = th_out[t]; }
    __syncthreads();

    // ---- phase B: gap-junction scatter (parallel over dst j), C, p4, q ----
    if (t < 64) {
        const int j = t;
        float m0 = 0.f, m1 = 0.f, m2 = 0.f, m3 = 0.f, deg = 0.f;
        #pragma unroll 4
        for (int e = 0; e < 128; ++e) {
            const float w = (sdst[e] == j) ? s[L_SW + e] : 0.0f;
            deg += w;
            const int se = ssrc[e];
            m0 += (se == 0) ? w : 0.0f;
            m1 += (se == 1) ? w : 0.0f;
            m2 += (se == 2) ? w : 0.0f;
            m3 += (se == 3) ? w : 0.0f;
        }
        s[L_C + 0*64 + j] = m0 - softplus_f(w_in2hid[0*64 + j]);
        s[L_C + 1*64 + j] = m1 - softplus_f(w_in2hid[1*64 + j]);
        s[L_C + 2*64 + j] = m2 - softplus_f(w_in2hid[2*64 + j]);
        s[L_C + 3*64 + j] = m3 - softplus_f(w_in2hid[3*64 + j]);
        const float a  = dec_hid[j] - deg;
        const float a2 = a * a;
        s[L_P4 + j] = a2 * a2;
        s[L_Q + j]  = 1.0f + a + a2 + a2 * a;
    }
    __syncthreads();

    const int b = blockIdx.x * NTHREADS + t;
    if (b >= B) return;

    const float4 xv = *(const float4*)(x + (size_t)b * 4);

    // ---- I_const init: x @ C ----
    float I[64];
    {
        const float4* C4 = (const float4*)(s + L_C);
        #pragma unroll
        for (int j4 = 0; j4 < 16; ++j4) {
            const float4 c0 = C4[j4], c1 = C4[16 + j4], c2 = C4[32 + j4], c3 = C4[48 + j4];
            I[4*j4+0] = xv.x*c0.x + xv.y*c1.x + xv.z*c2.x + xv.w*c3.x;
            I[4*j4+1] = xv.x*c0.y + xv.y*c1.y + xv.z*c2.y + xv.w*c3.y;
            I[4*j4+2] = xv.x*c0.z + xv.y*c1.z + xv.z*c2.z + xv.w*c3.z;
            I[4*j4+3] = xv.x*c0.w + xv.y*c1.w + xv.z*c2.w + xv.w*c3.w;
        }
    }

    float h2o[8];
    #pragma unroll
    for (int o = 0; o < 8; ++o) h2o[o] = 0.0f;

    // ---- stream hid_O0 row; accumulate I += O0@W and h2o += O0@H ----
    const float4* O0row = (const float4*)(hidO0 + (size_t)b * 64);
    const float4* W4 = (const float4*)(s + L_W);   // [64][16] of float4
    const float4* H4 = (const float4*)(s + L_H);   // [64][2] of float4
    for (int kk = 0; kk < 16; ++kk) {
        const float4 o4 = O0row[kk];
        #pragma unroll
        for (int d = 0; d < 4; ++d) {
            const int k = kk * 4 + d;
            const float ok = (d == 0) ? o4.x : (d == 1) ? o4.y : (d == 2) ? o4.z : o4.w;
            #pragma unroll
            for (int j4 = 0; j4 < 16; ++j4) {
                const float4 w = W4[k*16 + j4];
                I[4*j4+0] = fmaf(ok, w.x, I[4*j4+0]);
                I[4*j4+1] = fmaf(ok, w.y, I[4*j4+1]);
                I[4*j4+2] = fmaf(ok, w.z, I[4*j4+2]);
                I[4*j4+3] = fmaf(ok, w.w, I[4*j4+3]);
            }
            const float4 ha = H4[k*2 + 0], hb = H4[k*2 + 1];
            h2o[0] = fmaf(ok, ha.x, h2o[0]);
            h2o[1] = fmaf(ok, ha.y, h2o[1]);
            h2o[2] = fmaf(ok, ha.z, h2o[2]);
            h2o[3] = fmaf(ok, ha.w, h2o[3]);
            h2o[4] = fmaf(ok, hb.x, h2o[4]);
            h2o[5] = fmaf(ok, hb.y, h2o[5]);
            h2o[6] = fmaf(ok, hb.z, h2o[6]);
            h2o[7] = fmaf(ok, hb.w, h2o[7]);
        }
    }

    float4* outv = (float4*)out;
    const size_t Bs = (size_t)B;

    // ---- E_in / O_in ----
    {
        const float4 di = *(const float4*)(s + L_SM);
        const float4 ti = *(const float4*)(s + L_SM + 4);
        float4 Ein, Oin;
        Ein.x = di.x * xv.x; Ein.y = di.y * xv.y; Ein.z = di.z * xv.z; Ein.w = di.w * xv.w;
        Oin.x = (Ein.x >= ti.x) ? Ein.x : 0.0f;
        Oin.y = (Ein.y >= ti.y) ? Ein.y : 0.0f;
        Oin.z = (Ein.z >= ti.z) ? Ein.z : 0.0f;
        Oin.w = (Ein.w >= ti.w) ? Ein.w : 0.0f;
        outv[Bs*2 + b] = Ein;   // E_in at elem offset B*8
        outv[Bs*3 + b] = Oin;   // O_in at elem offset B*12
    }

    // ---- E_hid / O_hid: E = a^4*E0 + (1+a+a^2+a^3)*I ----
    {
        const float4* E0row = (const float4*)(hidE0 + (size_t)b * 64);
        const float4* P44 = (const float4*)(s + L_P4);
        const float4* Q44 = (const float4*)(s + L_Q);
        const float4* T44 = (const float4*)(s + L_TH);
        #pragma unroll
        for (int j4 = 0; j4 < 16; ++j4) {
            const float4 e0 = E0row[j4];
            const float4 p = P44[j4], q = Q44[j4], th = T44[j4];
            float4 E, O;
            E.x = fmaf(p.x, e0.x, q.x * I[4*j4+0]);
            E.y = fmaf(p.y, e0.y, q.y * I[4*j4+1]);
            E.z = fmaf(p.z, e0.z, q.z * I[4*j4+2]);
            E.w = fmaf(p.w, e0.w, q.w * I[4*j4+3]);
            O.x = (E.x >= th.x) ? E.x : 0.0f;
            O.y = (E.y >= th.y) ? E.y : 0.0f;
            O.z = (E.z >= th.z) ? E.z : 0.0f;
            O.w = (E.w >= th.w) ? E.w : 0.0f;
            outv[Bs*4  + (size_t)b*16 + j4] = E;   // E_hid at elem offset B*16
            outv[Bs*20 + (size_t)b*16 + j4] = O;   // O_hid at elem offset B*80
        }
    }

    // ---- output layer ----
    {
        const float4* Eo0row = (const float4*)(outE0 + (size_t)b * 8);
        const float4 e0a = Eo0row[0], e0b = Eo0row[1];
        float Eo[8];
        Eo[0] = fmaf(s[L_SM + 8 + 0], e0a.x, h2o[0]);
        Eo[1] = fmaf(s[L_SM + 8 + 1], e0a.y, h2o[1]);
        Eo[2] = fmaf(s[L_SM + 8 + 2], e0a.z, h2o[2]);
        Eo[3] = fmaf(s[L_SM + 8 + 3], e0a.w, h2o[3]);
        Eo[4] = fmaf(s[L_SM + 8 + 4], e0b.x, h2o[4]);
        Eo[5] = fmaf(s[L_SM + 8 + 5], e0b.y, h2o[5]);
        Eo[6] = fmaf(s[L_SM + 8 + 6], e0b.z, h2o[6]);
        Eo[7] = fmaf(s[L_SM + 8 + 7], e0b.w, h2o[7]);

        float4 a0, a1, Ev0, Ev1, Ov0, Ov1;
        a0.x = tanhf(Eo[0]); a0.y = tanhf(Eo[1]); a0.z = tanhf(Eo[2]); a0.w = tanhf(Eo[3]);
        a1.x = tanhf(Eo[4]); a1.y = tanhf(Eo[5]); a1.z = tanhf(Eo[6]); a1.w = tanhf(Eo[7]);
        Ev0.x = Eo[0]; Ev0.y = Eo[1]; Ev0.z = Eo[2]; Ev0.w = Eo[3];
        Ev1.x = Eo[4]; Ev1.y = Eo[5]; Ev1.z = Eo[6]; Ev1.w = Eo[7];
        Ov0.x = (Eo[0] >= s[L_SM+16+0]) ? Eo[0] : 0.0f;
        Ov0.y = (Eo[1] >= s[L_SM+16+1]) ? Eo[1] : 0.0f;
        Ov0.z = (Eo[2] >= s[L_SM+16+2]) ? Eo[2] : 0.0f;
        Ov0.w = (Eo[3] >= s[L_SM+16+3]) ? Eo[3] : 0.0f;
        Ov1.x = (Eo[4] >= s[L_SM+16+4]) ? Eo[4] : 0.0f;
        Ov1.y = (Eo[5] >= s[L_SM+16+5]) ? Eo[5] : 0.0f;
        Ov1.z = (Eo[6] >= s[L_SM+16+6]) ? Eo[6] : 0.0f;
        Ov1.w = (Eo[7] >= s[L_SM+16+7]) ? Eo[7] : 0.0f;

        outv[(size_t)b*2 + 0]   = a0;            // action at elem offset 0
        outv[(size_t)b*2 + 1]   = a1;
        outv[Bs*36 + (size_t)b*2 + 0] = Ev0;     // E_out at elem offset B*144
        outv[Bs*36 + (size_t)b*2 + 1] = Ev1;
        outv[Bs*38 + (size_t)b*2 + 0] = Ov0;     // O_out at elem offset B*152
        outv[Bs*38 + (size_t)b*2 + 1] = Ov1;
    }
}

extern "C" void kernel_launch(void* const* d_in, const int* in_sizes, int n_in,
                              void* d_out, int out_size, void* d_ws, size_t ws_size,
                              hipStream_t stream) {
    (void)n_in; (void)out_size; (void)d_ws; (void)ws_size;
    const float* x        = (const float*)d_in[0];
    const float* hidE0    = (const float*)d_in[1];
    const float* hidO0    = (const float*)d_in[2];
    const float* outE0    = (const float*)d_in[3];
    // d_in[4] (out_O0) is unused by the reference
    const float* w_in2hid = (const float*)d_in[5];
    const float* w_hid_IN = (const float*)d_in[6];
    const float* w_hid_EX = (const float*)d_in[7];
    const float* w_hid2out= (const float*)d_in[8];
    const float* gj_w     = (const float*)d_in[9];
    const float* th_in    = (const float*)d_in[10];
    const float* dec_in   = (const float*)d_in[11];
    const float* th_hid   = (const float*)d_in[12];
    const float* dec_hid  = (const float*)d_in[13];
    const float* th_out   = (const float*)d_in[14];
    const float* dec_out  = (const float*)d_in[15];
    const int*   gj_src   = (const int*)d_in[16];
    const int*   gj_dst   = (const int*)d_in[17];
    float* out = (float*)d_out;

    const int B = in_sizes[0] / 4;
    const int grid = (B + NTHREADS - 1) / NTHREADS;
    twc_fused<<<grid, NTHREADS, 0, stream>>>(
        x, hidE0, hidO0, outE0, w_in2hid, w_hid_IN, w_hid_EX, w_hid2out,
        gj_w, th_in, dec_in, th_hid, dec_hid, th_out, dec_out,
        gj_src, gj_dst, out, B);
}